// Round 11
// baseline (74.409 us; speedup 1.0000x reference)
//
#include <hip/hip_runtime.h>

#define NB 64        // bins
#define HW 65536     // pixels per channel (256*256)
#define NCH 24       // B*C = 8*3
#define SPLIT 8      // segments per channel-image
#define NPAIR 38     // 76 slots as 38 float2 pairs; slot = bin + 6, bins -6..69

typedef __attribute__((ext_vector_type(4))) float f32x4;
typedef __attribute__((ext_vector_type(2))) float f32x2;

// w_j(x) = exp(-K*(f-j)^2), f = 63x, K = 2048/3969.
// Even-aligned 12-tap window: e0 = (rint(f)-5) & ~1, c0 = e0+6,
// d' = f - c0 in [-1.5, 0.5]; taps r = -6..5 -> bins e0..e0+11 (superset of
// the +-5 window; dropped mass < 1.5e-7 relative). 3 transcendentals, 12 taps.
//
// LDS: H[pair][256] float2; a pixel's 12 taps = 6 float2 cells 2048 B apart.
// r10/r11 change (single variable vs r9): 6 ds_read_b64 + 6 ds_write_b64 per
// pixel become 3 ds_read2st64_b64 + 3 ds_write2st64_b64 (st64 offsets are
// 512-B units; 2048 B = 4 units -> offset pairs 0,4 / 8,12 / 16,20; all < 256).
// Identical addresses, banks, semantics — only DS instruction COUNT halves
// (12 -> 6). Tests the surviving bottleneck hypothesis: fixed per-DS-instr
// issue cost (r1/r3/r7/r8 killed atomics/op-width/occupancy/schedule).
// Ordering: reads are volatile asm with dataflow outputs; pass-through
// lgkmcnt(0) + sched_barrier(0) before the adds (rule #18); volatile
// "memory" write asm + volatile read asm keeps cross-pixel RAW order
// (volatile asm blocks are never reordered against each other; LDS completes
// in order per wave).
__global__ __launch_bounds__(256) void chml_hist(const float* __restrict__ pred,
                                                 const float* __restrict__ targ,
                                                 float* __restrict__ part,
                                                 float* __restrict__ out) {
  const int seg = blockIdx.x;   // 0..SPLIT-1
  const int ct  = blockIdx.y;   // 0..2*NCH-1
  const float* src = (ct < NCH) ? (pred + (size_t)ct * HW)
                                : (targ + (size_t)(ct - NCH) * HW);
  const int tid = threadIdx.x;

  if (seg == 0 && ct == 0 && tid == 0) out[0] = 0.0f;  // for chan's atomicAdd

  // issue all 8 global float4 loads first (in flight during LDS init)
  const float4* s4 = (const float4*)(src + (size_t)seg * (HW / SPLIT));
  float4 P[8];
#pragma unroll
  for (int i = 0; i < 8; ++i) P[i] = s4[i * 256 + tid];

  __shared__ __align__(16) float2 H[NPAIR][256];   // 77824 B -> 2 blocks/CU
  {
    float4* hz = (float4*)&H[0][0];
#pragma unroll
    for (int i = tid; i < NPAIR * 256 * 2 / 4; i += 256)
      hz[i] = make_float4(0.f, 0.f, 0.f, 0.f);
  }
  __syncthreads();

  const float K  = 0.51599899f;      // 2048/3969
  const float C1 = 5.96905619e-01f;  // exp(-K*1)
  const float C2 = 1.26927917e-01f;  // exp(-K*4)
  const float C3 = 9.61165782e-03f;  // exp(-K*9)
  const float C4 = 2.59240329e-04f;  // exp(-K*16)
  const float C5 = 2.49029640e-06f;  // exp(-K*25)
  const float C6 = 8.56260000e-09f;  // exp(-K*36)

  // 32-bit LDS byte offset of this thread's column. The cast generic->AS(3)
  // lowers to addrspacecast (strips the flat aperture); truncating the AS(3)
  // pointer yields the LDS byte offset. tid*8 -> 8-B aligned for b64.
  typedef __attribute__((address_space(3))) float2 lds_f32x2;
  const unsigned hbase = (unsigned)(size_t)((lds_f32x2*)&H[0][0] + tid);

#pragma unroll
  for (int k2 = 0; k2 < 8; ++k2) {
    float4 p = P[k2];
    float pe[4] = {p.x, p.y, p.z, p.w};
#pragma unroll
    for (int e = 0; e < 4; ++e) {
      float f  = pe[e] * 63.0f;
      float n  = rintf(f);
      int   ni = (int)n;                        // 0..63
      int   e0 = (ni - 5) & ~1;                 // even, in [-6, 58]
      float dp = f - (float)(e0 + 6);           // d' in [-1.5, 0.5]
      int   p0 = (e0 >> 1) + 3;                 // first pair, 0..32
      unsigned a = hbase + ((unsigned)p0 << 11); // pair stride = 2048 B
      // ---- 3 read2st64: taps (0,1),(2,3),(4,5) [pairs 2048 B apart]
      f32x4 t01, t23, t45;
      asm volatile("ds_read2st64_b64 %0, %1 offset0:0 offset1:4"
                   : "=v"(t01) : "v"(a));
      asm volatile("ds_read2st64_b64 %0, %1 offset0:8 offset1:12"
                   : "=v"(t23) : "v"(a));
      asm volatile("ds_read2st64_b64 %0, %1 offset0:16 offset1:20"
                   : "=v"(t45) : "v"(a));
      // ---- weight ladder (independent of the reads -> overlaps latency)
      float w0 = __expf(dp * dp * -K);
      float mp = __expf(dp * (2.0f * K));
      float mn = __expf(dp * (-2.0f * K));
      float mp2 = mp * mp, mp3 = mp2 * mp, mp4 = mp2 * mp2, mp5 = mp4 * mp;
      float mn2 = mn * mn, mn3 = mn2 * mn, mn4 = mn2 * mn2, mn5 = mn4 * mn,
            mn6 = mn3 * mn3;
      float A1 = w0 * C1, A2 = w0 * C2, A3 = w0 * C3, A4 = w0 * C4,
            A5 = w0 * C5, A6 = w0 * C6;
      // ---- drain the reads; pass-through outputs keep the adds ordered
      asm volatile("s_waitcnt lgkmcnt(0)"
                   : "+v"(t01), "+v"(t23), "+v"(t45));
      __builtin_amdgcn_sched_barrier(0);
      f32x2 d0 = {t01.x + A6 * mn6, t01.y + A5 * mn5};  // r = -6, -5
      f32x2 d1 = {t01.z + A4 * mn4, t01.w + A3 * mn3};  // r = -4, -3
      f32x2 d2 = {t23.x + A2 * mn2, t23.y + A1 * mn};   // r = -2, -1
      f32x2 d3 = {t23.z + w0,       t23.w + A1 * mp};   // r =  0, +1
      f32x2 d4 = {t45.x + A2 * mp2, t45.y + A3 * mp3};  // r = +2, +3
      f32x2 d5 = {t45.z + A4 * mp4, t45.w + A5 * mp5};  // r = +4, +5
      // ---- 3 write2st64 RMW writeback
      asm volatile("ds_write2st64_b64 %2, %0, %1 offset0:0 offset1:4"
                   :: "v"(d0), "v"(d1), "v"(a) : "memory");
      asm volatile("ds_write2st64_b64 %2, %0, %1 offset0:8 offset1:12"
                   :: "v"(d2), "v"(d3), "v"(a) : "memory");
      asm volatile("ds_write2st64_b64 %2, %0, %1 offset0:16 offset1:20"
                   :: "v"(d4), "v"(d5), "v"(a) : "memory");
    }
  }
  __syncthreads();

  // Fold 256 columns -> 1 per pair. Lane l (<38) owns pair l; wave wv sums
  // rows [64wv, 64wv+64) with staggered row order (i+l)&63 -> uniform b64
  // banks, conflict-free.
  const int wv = tid >> 6, l = tid & 63;
  float2 facc = make_float2(0.f, 0.f);
  if (l < NPAIR) {
    const float2* col = &H[l][wv << 6];
#pragma unroll 8
    for (int i = 0; i < 64; ++i) {
      float2 v = col[(i + l) & 63];
      facc.x += v.x; facc.y += v.y;
    }
  }
  __syncthreads();
  if (l < NPAIR) H[l][wv] = facc;   // scratch: rows 0..3 (already consumed)
  __syncthreads();
  if (tid < NPAIR) {
    float2 a = H[tid][0], b2 = H[tid][1], c2 = H[tid][2], d2 = H[tid][3];
    float sx = a.x + b2.x + c2.x + d2.x;
    float sy = a.y + b2.y + c2.y + d2.y;
    int bin0 = 2 * tid - 6;          // slot 2*tid -> bin = slot - 6
    float* dst = part + ((size_t)ct * SPLIT + seg) * NB;
    if (bin0 >= 0 && bin0 < NB) dst[bin0] = sx;
    int bin1 = bin0 + 1;
    if (bin1 >= 0 && bin1 < NB) dst[bin1] = sy;
  }
}

// Merged tail: per-channel CDF loss, pre-scaled atomicAdd into out.
// 24 blocks x 64 threads (parallel across CUs — r5 lesson). out was zeroed
// by hist block (0,0); stream order makes this race-free.
__global__ __launch_bounds__(64) void chml_chan(const float* __restrict__ part,
                                                float* __restrict__ out) {
  const int c    = blockIdx.x;
  const int lane = threadIdx.x;
  float vp = 0.0f, vt = 0.0f;
#pragma unroll
  for (int s = 0; s < SPLIT; ++s) {
    vp += part[((size_t)c * SPLIT + s) * NB + lane];
    vt += part[((size_t)(c + NCH) * SPLIT + s) * NB + lane];
  }
  // inclusive prefix scan across 64 lanes
#pragma unroll
  for (int off = 1; off < 64; off <<= 1) {
    float up = __shfl_up(vp, off, 64);
    float ut = __shfl_up(vt, off, 64);
    if (lane >= off) { vp += up; vt += ut; }
  }
  float totp = __shfl(vp, 63, 64);
  float tott = __shfl(vt, 63, 64);
  float l = fabsf(vp / (totp + 1e-7f) - vt / (tott + 1e-7f));
#pragma unroll
  for (int off = 32; off >= 1; off >>= 1) l += __shfl_xor(l, off, 64);
  if (lane == 0) atomicAdd(out, l * (1.0f / (float)(NCH * NB)));
}

extern "C" void kernel_launch(void* const* d_in, const int* in_sizes, int n_in,
                              void* d_out, int out_size, void* d_ws, size_t ws_size,
                              hipStream_t stream) {
  const float* pred = (const float*)d_in[0];
  const float* targ = (const float*)d_in[1];
  float* part = (float*)d_ws;        // 48*8*64 floats = 96 KB

  dim3 grid(SPLIT, 2 * NCH);
  chml_hist<<<grid, 256, 0, stream>>>(pred, targ, part, (float*)d_out);
  chml_chan<<<NCH, 64, 0, stream>>>(part, (float*)d_out);
}